// Round 9
// baseline (314.076 us; speedup 1.0000x reference)
//
#include <hip/hip_runtime.h>
#include <hip/hip_bf16.h>
#include <math.h>

#define B_ 64
#define L_ 512
#define D_ 768
#define J_ 31
#define S_ 32
#define H_ 100
#define G3 300
#define NC_ 10
#define EMB_ 50
#define NCH 4            // batch chains per scan block

__device__ __forceinline__ float sigmoidf_(float x) { return 1.0f / (1.0f + __expf(-x)); }
__device__ __forceinline__ float tanhf_(float x) {
    float e = __expf(2.0f * x);
    return 1.0f - 2.0f / (e + 1.0f);
}

typedef _Float16 half2_t __attribute__((ext_vector_type(2)));
__device__ __forceinline__ half2_t u_as_h2(unsigned u) { return __builtin_bit_cast(half2_t, u); }
__device__ __forceinline__ unsigned packh2(float a, float b) {
    half2_t p; p.x = (_Float16)a; p.y = (_Float16)b;
    return __builtin_bit_cast(unsigned, p);
}

// ---------------------------------------------------------------------------
// K1: per-clause softmax-weighted pooling.  One block per (s, b).
// ---------------------------------------------------------------------------
#define TCAP 18
__global__ __launch_bounds__(256) void pool_kernel(
    const float* __restrict__ hs, const int* __restrict__ cb,
    const float* __restrict__ fc5w, const float* __restrict__ fc5b,
    float* __restrict__ doc)
{
    __shared__ __align__(16) float tile[TCAP * D_];
    __shared__ float sc_s[L_];
    __shared__ float red[8];

    int s = blockIdx.x, b = blockIdx.y;
    int start = (s == 0) ? 0 : cb[b * J_ + s - 1];
    int end   = (s == J_) ? L_ : cb[b * J_ + s];
    int nt = end - start;
    int tid = threadIdx.x;

    if (nt <= 0) {
        for (int d = tid; d < D_; d += 256) doc[((size_t)s * B_ + b) * D_ + d] = 0.f;
        return;
    }
    bool staged = (nt <= TCAP);
    const float* base = hs + ((size_t)b * L_ + start) * D_;

    if (staged) {
        const float4* b4 = (const float4*)base;
        float4* t4 = (float4*)tile;
        int n4 = nt * (D_ / 4);
        for (int i = tid; i < n4; i += 256) t4[i] = b4[i];
    }
    int lane = tid & 63, wv = tid >> 6;
    float fw[12];
#pragma unroll
    for (int i = 0; i < 12; ++i) fw[i] = fc5w[i * 64 + lane];
    __syncthreads();

    for (int t = wv; t < nt; t += 4) {
        const float* row = staged ? &tile[t * D_] : (base + (size_t)t * D_);
        float p = 0.f;
#pragma unroll
        for (int i = 0; i < 12; ++i) p += row[i * 64 + lane] * fw[i];
        for (int off = 32; off; off >>= 1) p += __shfl_xor(p, off);
        if (lane == 0) sc_s[t] = p + fc5b[0];
    }
    __syncthreads();

    float lm = -INFINITY;
    for (int i = tid; i < nt; i += 256) lm = fmaxf(lm, sc_s[i]);
    for (int off = 32; off; off >>= 1) lm = fmaxf(lm, __shfl_xor(lm, off));
    if (lane == 0) red[wv] = lm;
    __syncthreads();
    float mx = fmaxf(fmaxf(red[0], red[1]), fmaxf(red[2], red[3]));
    float ls = 0.f;
    for (int i = tid; i < nt; i += 256) {
        float e = __expf(sc_s[i] - mx);
        sc_s[i] = e;
        ls += e;
    }
    for (int off = 32; off; off >>= 1) ls += __shfl_xor(ls, off);
    if (lane == 0) red[4 + wv] = ls;
    __syncthreads();
    float inv = 1.f / (red[4] + red[5] + red[6] + red[7]);

    float acc0 = 0.f, acc1 = 0.f, acc2 = 0.f;
    for (int t = 0; t < nt; ++t) {
        float w = sc_s[t] * inv;
        const float* row = staged ? &tile[t * D_] : (base + (size_t)t * D_);
        acc0 += w * row[tid];
        acc1 += w * row[256 + tid];
        acc2 += w * row[512 + tid];
    }
    float* o = doc + ((size_t)s * B_ + b) * D_;
    o[tid] = acc0; o[256 + tid] = acc1; o[512 + tid] = acc2;
}

// ---------------------------------------------------------------------------
// K2: gi = doc @ [Wf;Wb].T + [bf;bb]   M=2048, N=600, K=768  (64x64 tiles)
// ---------------------------------------------------------------------------
__global__ __launch_bounds__(256) void gemm_enc(
    const float* __restrict__ A,
    const float* __restrict__ Wf, const float* __restrict__ Wb,
    const float* __restrict__ bf_, const float* __restrict__ bb_,
    float* __restrict__ C)
{
    __shared__ __align__(16) float As[16][68];
    __shared__ __align__(16) float Ws[16][68];
    int n0 = blockIdx.x * 64, m0 = blockIdx.y * 64;
    int tid = threadIdx.x;
    int tx = tid & 15, ty = tid >> 4;
    int lr = tid >> 2, lk4 = tid & 3;
    float acc[4][4] = {};

    for (int kk = 0; kk < D_; kk += 16) {
        float4 av = *(const float4*)(A + ((size_t)(m0 + lr)) * D_ + kk + lk4 * 4);
        As[lk4 * 4 + 0][lr] = av.x; As[lk4 * 4 + 1][lr] = av.y;
        As[lk4 * 4 + 2][lr] = av.z; As[lk4 * 4 + 3][lr] = av.w;
        int n = n0 + lr;
        float4 wvv = make_float4(0.f, 0.f, 0.f, 0.f);
        if (n < G3)      wvv = *(const float4*)(Wf + (size_t)n * D_ + kk + lk4 * 4);
        else if (n < 600) wvv = *(const float4*)(Wb + (size_t)(n - G3) * D_ + kk + lk4 * 4);
        Ws[lk4 * 4 + 0][lr] = wvv.x; Ws[lk4 * 4 + 1][lr] = wvv.y;
        Ws[lk4 * 4 + 2][lr] = wvv.z; Ws[lk4 * 4 + 3][lr] = wvv.w;
        __syncthreads();
#pragma unroll
        for (int k = 0; k < 16; ++k) {
            float4 a4 = *(const float4*)&As[k][ty * 4];
            float4 w4 = *(const float4*)&Ws[k][tx * 4];
            float ai[4] = {a4.x, a4.y, a4.z, a4.w};
            float wj[4] = {w4.x, w4.y, w4.z, w4.w};
#pragma unroll
            for (int i = 0; i < 4; ++i)
#pragma unroll
                for (int j = 0; j < 4; ++j) acc[i][j] += ai[i] * wj[j];
        }
        __syncthreads();
    }
#pragma unroll
    for (int j = 0; j < 4; ++j) {
        int n = n0 + tx * 4 + j;
        if (n >= 600) continue;
        float bias = (n < G3) ? bf_[n] : bb_[n - G3];
#pragma unroll
        for (int i = 0; i < 4; ++i) {
            int m = m0 + ty * 4 + i;
            C[(size_t)m * 600 + n] = acc[i][j] + bias;
        }
    }
}

// ---------------------------------------------------------------------------
// Scan matvec: Whh in LDS as packed f16 pairs (62.4 KB), SHARED by NCH=4
// batch chains per block.  Row thread j reads each weight octet once and
// applies it to 4 h-vectors (uniform-address broadcast reads).
// ---------------------------------------------------------------------------
#define NOCT 13
#define WTDN (NOCT * G3 * 4)   // 15600 dwords = 62.4 KB

#define STAGE_WTD(NT)                                                     \
    for (int idx = tid; idx < WTDN; idx += NT) {                          \
        int o = idx / (G3 * 4);                                           \
        int r = idx - o * (G3 * 4);                                       \
        int j = r >> 2, d = r & 3;                                        \
        int k0 = 8 * o + 2 * d;                                           \
        float w0 = (k0 < H_) ? whh[j * H_ + k0] : 0.f;                    \
        float w1 = (k0 + 1 < H_) ? whh[j * H_ + k0 + 1] : 0.f;            \
        wtd[idx] = packh2(w0, w1);                                        \
    }

// 4-chain matvec for row `tid`: acc[c] over 13 octets, write gh_s[c][tid]
#define MATVEC4(jrow)                                                     \
    {                                                                     \
        float ac[NCH][4];                                                 \
        _Pragma("unroll")                                                 \
        for (int c = 0; c < NCH; ++c) { ac[c][0]=ac[c][1]=ac[c][2]=ac[c][3]=0.f; } \
        _Pragma("unroll")                                                 \
        for (int o = 0; o < NOCT; ++o) {                                  \
            uint4 w = *(const uint4*)&wtd[(o * G3 + (jrow)) * 4];         \
            _Pragma("unroll")                                             \
            for (int c = 0; c < NCH; ++c) {                               \
                uint4 hh = *(const uint4*)&h2s[c * 56 + o * 4];           \
                ac[c][0] = __builtin_amdgcn_fdot2(u_as_h2(w.x), u_as_h2(hh.x), ac[c][0], false); \
                ac[c][1] = __builtin_amdgcn_fdot2(u_as_h2(w.y), u_as_h2(hh.y), ac[c][1], false); \
                ac[c][2] = __builtin_amdgcn_fdot2(u_as_h2(w.z), u_as_h2(hh.z), ac[c][2], false); \
                ac[c][3] = __builtin_amdgcn_fdot2(u_as_h2(w.w), u_as_h2(hh.w), ac[c][3], false); \
            }                                                             \
        }                                                                 \
        _Pragma("unroll")                                                 \
        for (int c = 0; c < NCH; ++c)                                     \
            gh_s[c * G3 + (jrow)] = bh + (ac[c][0] + ac[c][1]) + (ac[c][2] + ac[c][3]); \
    }

// ---------------------------------------------------------------------------
// K3: encoder scans. 32 blocks = (16 fwd + 16 bwd) x 4 chains, 512 threads.
// Phase A: matvec (tid<300, 4 chains) + g prefetch.  Phase B: gates (tid<400).
// ---------------------------------------------------------------------------
#define SCT 512
__global__ __launch_bounds__(SCT) void enc_scan(
    const float* __restrict__ gi,
    const float* __restrict__ whh_f, const float* __restrict__ whh_b,
    const float* __restrict__ bhh_f, const float* __restrict__ bhh_b,
    float* __restrict__ out1, float* __restrict__ hT)
{
    __shared__ __align__(16) unsigned wtd[WTDN];    // 62.4 KB
    __shared__ __align__(16) unsigned h2s[NCH * 56];
    __shared__ float gh_s[NCH * G3];

    int bid = blockIdx.x;
    bool bwd = (bid >= 16);
    int b0 = (bid & 15) * NCH;
    const float* whh = bwd ? whh_b : whh_f;
    const float* bhh = bwd ? bhh_b : bhh_f;
    int tid = threadIdx.x;

    STAGE_WTD(SCT)
    if (tid < NCH * 56) h2s[tid] = 0u;
    float bh = (tid < G3) ? bhh[tid] : 0.f;
    int cg = tid / 100, jg = tid - cg * 100;        // gate role (tid < 400)
    float hc = 0.f;
    __syncthreads();

    const int goff = bwd ? G3 : 0;
    const int ooff = bwd ? H_ : 0;

    for (int step = 0; step < S_; ++step) {
        int t = bwd ? (S_ - 1 - step) : step;
        float ga0 = 0.f, ga1 = 0.f, ga2 = 0.f;
        if (tid < 400) {
            const float* g = gi + ((size_t)t * B_ + b0 + cg) * 600 + goff;
            ga0 = g[jg]; ga1 = g[100 + jg]; ga2 = g[200 + jg];
        }
        if (tid < G3) MATVEC4(tid)
        __syncthreads();
        if (tid < 400) {
            float r = sigmoidf_(ga0 + gh_s[cg * G3 + jg]);
            float z = sigmoidf_(ga1 + gh_s[cg * G3 + 100 + jg]);
            float n = tanhf_(ga2 + r * gh_s[cg * G3 + 200 + jg]);
            float hn = (1.f - z) * n + z * hc;
            hc = hn;
            out1[((size_t)t * B_ + b0 + cg) * 200 + ooff + jg] = hn;
            float hnn = __shfl_down(hn, 1);          // even-tid pairs: same wave
            if ((tid & 1) == 0) h2s[cg * 56 + (jg >> 1)] = packh2(hn, hnn);
        }
        __syncthreads();
    }
    if (!bwd && tid < 400) hT[(b0 + cg) * H_ + jg] = hc;
}

// ---------------------------------------------------------------------------
// K4a: W2[n] = dwih[n][50:150] @ l1w ; b2[n] ; tcg[c][n] = bih[n]+emb[c].dwih[n][0:50]
// ---------------------------------------------------------------------------
__global__ __launch_bounds__(256) void w2_precompute(
    const float* __restrict__ dwih, const float* __restrict__ l1w,
    const float* __restrict__ l1b, const float* __restrict__ emb,
    const float* __restrict__ bih,
    float* __restrict__ W2, float* __restrict__ b2, float* __restrict__ tcg)
{
    __shared__ float dw_s[H_];
    int n = blockIdx.x;
    int k = threadIdx.x;
    if (k < H_) dw_s[k] = dwih[(size_t)n * 150 + 50 + k];
    __syncthreads();
    if (k < 200) {
        float acc = 0.f;
        for (int i = 0; i < H_; ++i) acc += dw_s[i] * l1w[(size_t)i * 200 + k];
        W2[(size_t)n * 200 + k] = acc;
    } else if (k == 200) {
        float acc = 0.f;
        for (int i = 0; i < H_; ++i) acc += dw_s[i] * l1b[i];
        b2[n] = acc;
    } else if (k < 211) {
        int c = k - 201;
        float acc = bih[n];
        const float* er = emb + c * EMB_;
        const float* wr = dwih + (size_t)n * 150;
        for (int e = 0; e < EMB_; ++e) acc += er[e] * wr[e];
        tcg[c * G3 + n] = acc;
    }
}

// ---------------------------------------------------------------------------
// K4b: generic small NT GEMM
// ---------------------------------------------------------------------------
__global__ void small_gemm(
    const float* __restrict__ A, int lda, int K,
    const float* __restrict__ W, int wstride, int woff,
    const float* __restrict__ bias,
    float* __restrict__ C, int N, int ldc,
    int BM, int nChunk)
{
    extern __shared__ float sm[];
    int Kp = K + 1;
    float* Wl = sm;
    float* Al = sm + (size_t)nChunk * Kp;
    int nBase = blockIdx.x * nChunk;
    int nCnt = min(nChunk, N - nBase);
    int m0 = blockIdx.y * BM;

    for (int i = threadIdx.x; i < nCnt * K; i += blockDim.x) {
        int n = i / K, k = i - n * K;
        Wl[n * Kp + k] = W[(size_t)(nBase + n) * wstride + woff + k];
    }
    for (int i = threadIdx.x; i < BM * K; i += blockDim.x) {
        int mi = i / K, k = i - mi * K;
        Al[mi * Kp + k] = A[(size_t)(m0 + mi) * lda + k];
    }
    __syncthreads();

    for (int o = threadIdx.x; o < BM * nCnt; o += blockDim.x) {
        int mi = o / nCnt, n = o - mi * nCnt;
        const float* wr = &Wl[n * Kp];
        const float* ar = &Al[mi * Kp];
        float a0 = 0.f, a1 = 0.f, a2 = 0.f, a3 = 0.f;
        int k = 0;
        for (; k + 4 <= K; k += 4) {
            a0 += ar[k] * wr[k];
            a1 += ar[k + 1] * wr[k + 1];
            a2 += ar[k + 2] * wr[k + 2];
            a3 += ar[k + 3] * wr[k + 3];
        }
        for (; k < K; ++k) a0 += ar[k] * wr[k];
        float v = (a0 + a1) + (a2 + a3);
        if (bias) v += bias[nBase + n];
        C[(size_t)(m0 + mi) * ldc + nBase + n] = v;
    }
}

// ---------------------------------------------------------------------------
// K5: decoder scan. 16 blocks x 4 chains, 512 threads (8 waves).
// Phase A: matvec (tid<300) + wave 7 logits/argmax/log-softmax of step t-1
// (16-lane group per chain).  Phase B: gates (tid<400).  2 barriers/step.
// ---------------------------------------------------------------------------
__global__ __launch_bounds__(SCT) void dec_scan(
    const float* __restrict__ gi_lin,
    const float* __restrict__ whh, const float* __restrict__ bhh,
    const float* __restrict__ tcg,
    const float* __restrict__ h2lw, const float* __restrict__ h2lb,
    const float* __restrict__ hT, float* __restrict__ out)
{
    __shared__ __align__(16) unsigned wtd[WTDN];    // 62.4 KB
    __shared__ float tc_s[NC_ * G3];                // 12 KB
    __shared__ float hl_s[NC_ * H_];                // 4 KB
    __shared__ __align__(16) unsigned h2s[NCH * 56];
    __shared__ float hf[NCH * 104];
    __shared__ float gh_s[NCH * G3];
    __shared__ int prev_s[NCH];

    int b0 = blockIdx.x * NCH;
    int tid = threadIdx.x;

    STAGE_WTD(SCT)
    for (int idx = tid; idx < NC_ * G3; idx += SCT) tc_s[idx] = tcg[idx];
    for (int idx = tid; idx < NC_ * H_; idx += SCT) hl_s[idx] = h2lw[idx];
    if (tid < NCH * 56) h2s[tid] = 0u;

    float bh = (tid < G3) ? bhh[tid] : 0.f;
    int cg = tid / 100, jg = tid - cg * 100;        // gate role (tid < 400)
    float hc = 0.f;
    if (tid < 400) {
        hc = hT[(b0 + cg) * H_ + jg];
        hf[cg * 104 + jg] = hc;
    }
    if (tid < NCH * 50) {
        int c = tid / 50, p = tid - c * 50;
        h2s[c * 56 + p] = packh2(hT[(b0 + c) * H_ + 2 * p], hT[(b0 + c) * H_ + 2 * p + 1]);
    }
    if (tid < NCH) prev_s[tid] = 0;
    int l7 = tid - 448;                             // wave-7 lane if >= 0
    int c7 = l7 >> 4, cls7 = l7 & 15;
    float hlb_r = (l7 >= 0 && cls7 < NC_) ? h2lb[cls7] : 0.f;
    __syncthreads();

    for (int t = 0; t <= S_; ++t) {
        float ga0 = 0.f, ga1 = 0.f, ga2 = 0.f;
        if (t < S_ && tid < 400) {
            const float* g = gi_lin + ((size_t)t * B_ + b0 + cg) * G3;
            ga0 = g[jg]; ga1 = g[100 + jg]; ga2 = g[200 + jg];
        }
        if (tid < G3) {
            if (t < S_) MATVEC4(tid)
        } else if (l7 >= 0 && t >= 1) {
            // wave 7: logits for step t-1; 16-lane group per chain
            float v = -INFINITY;
            if (cls7 < NC_) {
                float acc = hlb_r;
                const float* hr = hl_s + cls7 * H_;
                const float* hv = hf + c7 * 104;
                for (int k = 0; k < H_; k += 4) {
                    acc += hr[k] * hv[k] + hr[k + 1] * hv[k + 1]
                         + hr[k + 2] * hv[k + 2] + hr[k + 3] * hv[k + 3];
                }
                v = acc;
            }
            float mx = v; int am = cls7;
#pragma unroll
            for (int m = 8; m; m >>= 1) {           // stays within 16-lane group
                float ov = __shfl_xor(mx, m);
                int   oa = __shfl_xor(am, m);
                if (ov > mx || (ov == mx && oa < am)) { mx = ov; am = oa; }
            }
            float e = (cls7 < NC_) ? __expf(v - mx) : 0.f;
            float se = e;
#pragma unroll
            for (int m = 8; m; m >>= 1) se += __shfl_xor(se, m);
            float lse = mx + __logf(se);
            if (cls7 < NC_) out[((size_t)(t - 1) * B_ + b0 + c7) * NC_ + cls7] = v - lse;
            if (cls7 == 0) prev_s[c7] = am;
        }
        __syncthreads();   // gh_s + prev_s ready; hf consumed
        if (t < S_ && tid < 400) {
            const float* tc = tc_s + prev_s[cg] * G3;
            float r = sigmoidf_(ga0 + tc[jg]       + gh_s[cg * G3 + jg]);
            float z = sigmoidf_(ga1 + tc[100 + jg] + gh_s[cg * G3 + 100 + jg]);
            float n = tanhf_(   ga2 + tc[200 + jg] + r * gh_s[cg * G3 + 200 + jg]);
            float hn = (1.f - z) * n + z * hc;
            hc = hn;
            hf[cg * 104 + jg] = hn;
            float hnn = __shfl_down(hn, 1);          // even-tid pairs: same wave
            if ((tid & 1) == 0) h2s[cg * 56 + (jg >> 1)] = packh2(hn, hnn);
        }
        __syncthreads();   // h2s/hf ready for next phase A
    }
}

// ---------------------------------------------------------------------------
extern "C" void kernel_launch(void* const* d_in, const int* in_sizes, int n_in,
                              void* d_out, int out_size, void* d_ws, size_t ws_size,
                              hipStream_t stream)
{
    const float* hs   = (const float*)d_in[0];
    const int*   cb   = (const int*)  d_in[1];
    const float* fc5w = (const float*)d_in[2];
    const float* fc5b = (const float*)d_in[3];
    const float* ewif = (const float*)d_in[4];
    const float* ewhf = (const float*)d_in[5];
    const float* ebif = (const float*)d_in[6];
    const float* ebhf = (const float*)d_in[7];
    const float* ewib = (const float*)d_in[8];
    const float* ewhb = (const float*)d_in[9];
    const float* ebib = (const float*)d_in[10];
    const float* ebhb = (const float*)d_in[11];
    const float* emb  = (const float*)d_in[12];
    const float* l1w  = (const float*)d_in[13];
    const float* l1b  = (const float*)d_in[14];
    const float* dwih = (const float*)d_in[15];
    const float* dwhh = (const float*)d_in[16];
    const float* dbih = (const float*)d_in[17];
    const float* dbhh = (const float*)d_in[18];
    const float* h2lw = (const float*)d_in[19];
    const float* h2lb = (const float*)d_in[20];
    float* out = (float*)d_out;

    float* ws   = (float*)d_ws;
    float* doc  = ws;                  // [32*64, 768]   = 1572864
    float* gi   = doc  + 1572864;      // [2048, 600]    = 1228800
    float* out1 = gi   + 1228800;      // [2048, 200]    = 409600
    float* hT   = out1 + 409600;       // [64, 100]      = 6400
    float* W2   = hT   + 6400;         // [300, 200]     = 60000
    float* b2   = W2   + 60000;        // [300]
    float* tcg  = b2   + 320;          // [10, 300]      = 3000
    float* gil  = tcg  + 3072;         // [2048, 300]    = 614400

    pool_kernel<<<dim3(S_, B_), 256, 0, stream>>>(hs, cb, fc5w, fc5b, doc);
    w2_precompute<<<G3, 256, 0, stream>>>(dwih, l1w, l1b, emb, dbih, W2, b2, tcg);
    gemm_enc<<<dim3(10, 32), 256, 0, stream>>>(doc, ewif, ewib, ebif, ebib, gi);
    enc_scan<<<32, SCT, 0, stream>>>(gi, ewhf, ewhb, ebhf, ebhb, out1, hT);
    {   // gil = out1 @ W2.T + b2   [2048,200]x[300,200] -> [2048,300]
        size_t sh = (size_t)(64 + 8) * 201 * sizeof(float);
        small_gemm<<<dim3(5, 256), 256, sh, stream>>>(out1, 200, 200,
                                                      W2, 200, 0, b2,
                                                      gil, 300, 300, 8, 64);
    }
    dec_scan<<<16, SCT, 0, stream>>>(gil, dwhh, dbhh, tcg,
                                     h2lw, h2lb, hT, out);
}

// Round 10
// 277.877 us; speedup vs baseline: 1.1303x; 1.1303x over previous
//
#include <hip/hip_runtime.h>
#include <hip/hip_bf16.h>
#include <math.h>

#define B_ 64
#define L_ 512
#define D_ 768
#define J_ 31
#define S_ 32
#define H_ 100
#define G3 300
#define NC_ 10
#define EMB_ 50

__device__ __forceinline__ float sigmoidf_(float x) { return 1.0f / (1.0f + __expf(-x)); }
__device__ __forceinline__ float tanhf_(float x) {
    float e = __expf(2.0f * x);
    return 1.0f - 2.0f / (e + 1.0f);
}

typedef _Float16 half2_t __attribute__((ext_vector_type(2)));
__device__ __forceinline__ half2_t u_as_h2(unsigned u) { return __builtin_bit_cast(half2_t, u); }
__device__ __forceinline__ unsigned packh2(float a, float b) {
    half2_t p; p.x = (_Float16)a; p.y = (_Float16)b;
    return __builtin_bit_cast(unsigned, p);
}

// ---------------------------------------------------------------------------
// K1: per-clause softmax-weighted pooling.  One block per (s, b).
// ---------------------------------------------------------------------------
#define TCAP 18
__global__ __launch_bounds__(256) void pool_kernel(
    const float* __restrict__ hs, const int* __restrict__ cb,
    const float* __restrict__ fc5w, const float* __restrict__ fc5b,
    float* __restrict__ doc)
{
    __shared__ __align__(16) float tile[TCAP * D_];
    __shared__ float sc_s[L_];
    __shared__ float red[8];

    int s = blockIdx.x, b = blockIdx.y;
    int start = (s == 0) ? 0 : cb[b * J_ + s - 1];
    int end   = (s == J_) ? L_ : cb[b * J_ + s];
    int nt = end - start;
    int tid = threadIdx.x;

    if (nt <= 0) {
        for (int d = tid; d < D_; d += 256) doc[((size_t)s * B_ + b) * D_ + d] = 0.f;
        return;
    }
    bool staged = (nt <= TCAP);
    const float* base = hs + ((size_t)b * L_ + start) * D_;

    if (staged) {
        const float4* b4 = (const float4*)base;
        float4* t4 = (float4*)tile;
        int n4 = nt * (D_ / 4);
        for (int i = tid; i < n4; i += 256) t4[i] = b4[i];
    }
    int lane = tid & 63, wv = tid >> 6;
    float fw[12];
#pragma unroll
    for (int i = 0; i < 12; ++i) fw[i] = fc5w[i * 64 + lane];
    __syncthreads();

    for (int t = wv; t < nt; t += 4) {
        const float* row = staged ? &tile[t * D_] : (base + (size_t)t * D_);
        float p = 0.f;
#pragma unroll
        for (int i = 0; i < 12; ++i) p += row[i * 64 + lane] * fw[i];
        for (int off = 32; off; off >>= 1) p += __shfl_xor(p, off);
        if (lane == 0) sc_s[t] = p + fc5b[0];
    }
    __syncthreads();

    float lm = -INFINITY;
    for (int i = tid; i < nt; i += 256) lm = fmaxf(lm, sc_s[i]);
    for (int off = 32; off; off >>= 1) lm = fmaxf(lm, __shfl_xor(lm, off));
    if (lane == 0) red[wv] = lm;
    __syncthreads();
    float mx = fmaxf(fmaxf(red[0], red[1]), fmaxf(red[2], red[3]));
    float ls = 0.f;
    for (int i = tid; i < nt; i += 256) {
        float e = __expf(sc_s[i] - mx);
        sc_s[i] = e;
        ls += e;
    }
    for (int off = 32; off; off >>= 1) ls += __shfl_xor(ls, off);
    if (lane == 0) red[4 + wv] = ls;
    __syncthreads();
    float inv = 1.f / (red[4] + red[5] + red[6] + red[7]);

    float acc0 = 0.f, acc1 = 0.f, acc2 = 0.f;
    for (int t = 0; t < nt; ++t) {
        float w = sc_s[t] * inv;
        const float* row = staged ? &tile[t * D_] : (base + (size_t)t * D_);
        acc0 += w * row[tid];
        acc1 += w * row[256 + tid];
        acc2 += w * row[512 + tid];
    }
    float* o = doc + ((size_t)s * B_ + b) * D_;
    o[tid] = acc0; o[256 + tid] = acc1; o[512 + tid] = acc2;
}

// ---------------------------------------------------------------------------
// K2: gi = doc @ [Wf;Wb].T + [bf;bb]   M=2048, N=600, K=768  (64x64 tiles)
// ---------------------------------------------------------------------------
__global__ __launch_bounds__(256) void gemm_enc(
    const float* __restrict__ A,
    const float* __restrict__ Wf, const float* __restrict__ Wb,
    const float* __restrict__ bf_, const float* __restrict__ bb_,
    float* __restrict__ C)
{
    __shared__ __align__(16) float As[16][68];
    __shared__ __align__(16) float Ws[16][68];
    int n0 = blockIdx.x * 64, m0 = blockIdx.y * 64;
    int tid = threadIdx.x;
    int tx = tid & 15, ty = tid >> 4;
    int lr = tid >> 2, lk4 = tid & 3;
    float acc[4][4] = {};

    for (int kk = 0; kk < D_; kk += 16) {
        float4 av = *(const float4*)(A + ((size_t)(m0 + lr)) * D_ + kk + lk4 * 4);
        As[lk4 * 4 + 0][lr] = av.x; As[lk4 * 4 + 1][lr] = av.y;
        As[lk4 * 4 + 2][lr] = av.z; As[lk4 * 4 + 3][lr] = av.w;
        int n = n0 + lr;
        float4 wvv = make_float4(0.f, 0.f, 0.f, 0.f);
        if (n < G3)      wvv = *(const float4*)(Wf + (size_t)n * D_ + kk + lk4 * 4);
        else if (n < 600) wvv = *(const float4*)(Wb + (size_t)(n - G3) * D_ + kk + lk4 * 4);
        Ws[lk4 * 4 + 0][lr] = wvv.x; Ws[lk4 * 4 + 1][lr] = wvv.y;
        Ws[lk4 * 4 + 2][lr] = wvv.z; Ws[lk4 * 4 + 3][lr] = wvv.w;
        __syncthreads();
#pragma unroll
        for (int k = 0; k < 16; ++k) {
            float4 a4 = *(const float4*)&As[k][ty * 4];
            float4 w4 = *(const float4*)&Ws[k][tx * 4];
            float ai[4] = {a4.x, a4.y, a4.z, a4.w};
            float wj[4] = {w4.x, w4.y, w4.z, w4.w};
#pragma unroll
            for (int i = 0; i < 4; ++i)
#pragma unroll
                for (int j = 0; j < 4; ++j) acc[i][j] += ai[i] * wj[j];
        }
        __syncthreads();
    }
#pragma unroll
    for (int j = 0; j < 4; ++j) {
        int n = n0 + tx * 4 + j;
        if (n >= 600) continue;
        float bias = (n < G3) ? bf_[n] : bb_[n - G3];
#pragma unroll
        for (int i = 0; i < 4; ++i) {
            int m = m0 + ty * 4 + i;
            C[(size_t)m * 600 + n] = acc[i][j] + bias;
        }
    }
}

// ---------------------------------------------------------------------------
// Scan core: weights in REGISTERS (f16-packed, 39 dwords/thread), h in LDS
// as a 104-entry f16 array (broadcast b32 reads).  Thread (j,q): rows
// {j,100+j,200+j}, h dwords 13q..13q+12 (k = 26q..26q+25); shfl_xor(1,2)
// combines quarters.  No LDS weight traffic at all.
// ---------------------------------------------------------------------------
#define LOAD_WREGS                                                          \
    unsigned wr_[13], wz_[13], wn_[13];                                     \
    if (mv) {                                                               \
        int d0 = 13 * q;                                                    \
        _Pragma("unroll")                                                   \
        for (int d = 0; d < 13; ++d) {                                      \
            int k = 2 * (d0 + d);                                           \
            float a0 = (k < H_)     ? whh[j * H_ + k]     : 0.f;            \
            float a1 = (k + 1 < H_) ? whh[j * H_ + k + 1] : 0.f;            \
            wr_[d] = packh2(a0, a1);                                        \
            a0 = (k < H_)     ? whh[(100 + j) * H_ + k]     : 0.f;          \
            a1 = (k + 1 < H_) ? whh[(100 + j) * H_ + k + 1] : 0.f;          \
            wz_[d] = packh2(a0, a1);                                        \
            a0 = (k < H_)     ? whh[(200 + j) * H_ + k]     : 0.f;          \
            a1 = (k + 1 < H_) ? whh[(200 + j) * H_ + k + 1] : 0.f;          \
            wn_[d] = packh2(a0, a1);                                        \
        }                                                                   \
    }

#define MATVEC_REG(PBUF)                                                    \
    {                                                                       \
        const unsigned* hh = (const unsigned*)(PBUF);                       \
        _Pragma("unroll")                                                   \
        for (int d = 0; d < 13; ++d) {                                      \
            half2_t hv = u_as_h2(hh[13 * q + d]);                           \
            ar = __builtin_amdgcn_fdot2(u_as_h2(wr_[d]), hv, ar, false);    \
            az = __builtin_amdgcn_fdot2(u_as_h2(wz_[d]), hv, az, false);    \
            an = __builtin_amdgcn_fdot2(u_as_h2(wn_[d]), hv, an, false);    \
        }                                                                   \
        ar += __shfl_xor(ar, 1); ar += __shfl_xor(ar, 2);                   \
        az += __shfl_xor(az, 1); az += __shfl_xor(az, 2);                   \
        an += __shfl_xor(an, 1); an += __shfl_xor(an, 2);                   \
    }

// ---------------------------------------------------------------------------
// K3: encoder scans. 128 blocks = (b, dir), 448 threads (7 waves),
// ONE barrier per step (double-buffered f16 h).
// ---------------------------------------------------------------------------
#define ENCT 448
__global__ __launch_bounds__(ENCT, 1) void enc_scan(
    const float* __restrict__ gi,
    const float* __restrict__ whh_f, const float* __restrict__ whh_b,
    const float* __restrict__ bhh_f, const float* __restrict__ bhh_b,
    float* __restrict__ out1, float* __restrict__ hT)
{
    __shared__ __align__(8) _Float16 hhalf[2][104];

    int bid = blockIdx.x;
    int b = bid & 63;
    bool bwd = (bid >= 64);
    const float* whh = bwd ? whh_b : whh_f;
    const float* bhh = bwd ? bhh_b : bhh_f;
    int tid = threadIdx.x;
    int j = tid >> 2, q = tid & 3;
    bool mv = tid < 400;

    if (tid < 104) { hhalf[0][tid] = (_Float16)0.f; hhalf[1][tid] = (_Float16)0.f; }
    LOAD_WREGS
    float bhr = 0.f, bhz = 0.f, bhn = 0.f, hc = 0.f;
    if (mv && q == 0) { bhr = bhh[j]; bhz = bhh[100 + j]; bhn = bhh[200 + j]; }
    __syncthreads();

    const int goff = bwd ? G3 : 0;
    const int ooff = bwd ? H_ : 0;
    int p = 0;
    for (int step = 0; step < S_; ++step) {
        int t = bwd ? (S_ - 1 - step) : step;
        if (mv) {
            float ga0 = 0.f, ga1 = 0.f, ga2 = 0.f;
            if (q == 0) {
                const float* g = gi + ((size_t)t * B_ + b) * 600 + goff;
                ga0 = g[j]; ga1 = g[100 + j]; ga2 = g[200 + j];
            }
            float ar = 0.f, az = 0.f, an = 0.f;
            MATVEC_REG(hhalf[p])
            if (q == 0) {
                float r = sigmoidf_(ga0 + ar + bhr);
                float z = sigmoidf_(ga1 + az + bhz);
                float n = tanhf_(ga2 + r * (an + bhn));
                float hn = (1.f - z) * n + z * hc;
                hc = hn;
                hhalf[p ^ 1][j] = (_Float16)hn;
                out1[((size_t)t * B_ + b) * 200 + ooff + j] = hn;
            }
        }
        __syncthreads();
        p ^= 1;
    }
    if (!bwd && mv && q == 0) hT[b * H_ + j] = hc;
}

// ---------------------------------------------------------------------------
// K4a: W2[n] = dwih[n][50:150] @ l1w ; b2[n] ; tcg[c][n] = bih[n]+emb[c].dwih[n][0:50]
// ---------------------------------------------------------------------------
__global__ __launch_bounds__(256) void w2_precompute(
    const float* __restrict__ dwih, const float* __restrict__ l1w,
    const float* __restrict__ l1b, const float* __restrict__ emb,
    const float* __restrict__ bih,
    float* __restrict__ W2, float* __restrict__ b2, float* __restrict__ tcg)
{
    __shared__ float dw_s[H_];
    int n = blockIdx.x;
    int k = threadIdx.x;
    if (k < H_) dw_s[k] = dwih[(size_t)n * 150 + 50 + k];
    __syncthreads();
    if (k < 200) {
        float acc = 0.f;
        for (int i = 0; i < H_; ++i) acc += dw_s[i] * l1w[(size_t)i * 200 + k];
        W2[(size_t)n * 200 + k] = acc;
    } else if (k == 200) {
        float acc = 0.f;
        for (int i = 0; i < H_; ++i) acc += dw_s[i] * l1b[i];
        b2[n] = acc;
    } else if (k < 211) {
        int c = k - 201;
        float acc = bih[n];
        const float* er = emb + c * EMB_;
        const float* wr = dwih + (size_t)n * 150;
        for (int e = 0; e < EMB_; ++e) acc += er[e] * wr[e];
        tcg[c * G3 + n] = acc;
    }
}

// ---------------------------------------------------------------------------
// K4b: generic small NT GEMM
// ---------------------------------------------------------------------------
__global__ void small_gemm(
    const float* __restrict__ A, int lda, int K,
    const float* __restrict__ W, int wstride, int woff,
    const float* __restrict__ bias,
    float* __restrict__ C, int N, int ldc,
    int BM, int nChunk)
{
    extern __shared__ float sm[];
    int Kp = K + 1;
    float* Wl = sm;
    float* Al = sm + (size_t)nChunk * Kp;
    int nBase = blockIdx.x * nChunk;
    int nCnt = min(nChunk, N - nBase);
    int m0 = blockIdx.y * BM;

    for (int i = threadIdx.x; i < nCnt * K; i += blockDim.x) {
        int n = i / K, k = i - n * K;
        Wl[n * Kp + k] = W[(size_t)(nBase + n) * wstride + woff + k];
    }
    for (int i = threadIdx.x; i < BM * K; i += blockDim.x) {
        int mi = i / K, k = i - mi * K;
        Al[mi * Kp + k] = A[(size_t)(m0 + mi) * lda + k];
    }
    __syncthreads();

    for (int o = threadIdx.x; o < BM * nCnt; o += blockDim.x) {
        int mi = o / nCnt, n = o - mi * nCnt;
        const float* wr = &Wl[n * Kp];
        const float* ar = &Al[mi * Kp];
        float a0 = 0.f, a1 = 0.f, a2 = 0.f, a3 = 0.f;
        int k = 0;
        for (; k + 4 <= K; k += 4) {
            a0 += ar[k] * wr[k];
            a1 += ar[k + 1] * wr[k + 1];
            a2 += ar[k + 2] * wr[k + 2];
            a3 += ar[k + 3] * wr[k + 3];
        }
        for (; k < K; ++k) a0 += ar[k] * wr[k];
        float v = (a0 + a1) + (a2 + a3);
        if (bias) v += bias[nBase + n];
        C[(size_t)(m0 + mi) * ldc + nBase + n] = v;
    }
}

// ---------------------------------------------------------------------------
// K5: decoder scan. 64 blocks (one per batch elem), 512 threads (8 waves).
// Threads 0-399: register-weight matvec + gates.  Wave 7 (448+): logits/
// argmax/log-softmax of step t-1 (f32 hf) concurrent with matvec.
// 2 barriers/step (prev_s handoff).
// ---------------------------------------------------------------------------
#define DECT 512
__global__ __launch_bounds__(DECT, 1) void dec_scan(
    const float* __restrict__ gi_lin,
    const float* __restrict__ whh, const float* __restrict__ bhh,
    const float* __restrict__ tcg,
    const float* __restrict__ h2lw, const float* __restrict__ h2lb,
    const float* __restrict__ hT, float* __restrict__ out)
{
    __shared__ float tc_s[NC_ * G3];               // 12 KB
    __shared__ float hl_s[NC_ * H_];               // 4 KB
    __shared__ __align__(8) _Float16 hhalf[2][104];
    __shared__ float hf[104];
    __shared__ int prev_s;

    int b = blockIdx.x;
    int tid = threadIdx.x;
    int j = tid >> 2, q = tid & 3;
    bool mv = tid < 400;

    for (int idx = tid; idx < NC_ * G3; idx += DECT) tc_s[idx] = tcg[idx];
    for (int idx = tid; idx < NC_ * H_; idx += DECT) hl_s[idx] = h2lw[idx];
    if (tid < 104) {
        float hv = (tid < H_) ? hT[b * H_ + tid] : 0.f;
        hf[tid] = hv;
        hhalf[0][tid] = (_Float16)hv;
        hhalf[1][tid] = (_Float16)0.f;
    }
    if (tid == 0) prev_s = 0;

    LOAD_WREGS
    float bhr = 0.f, bhz = 0.f, bhn = 0.f, hc = 0.f;
    if (mv && q == 0) {
        bhr = bhh[j]; bhz = bhh[100 + j]; bhn = bhh[200 + j];
        hc = hT[b * H_ + j];
    }
    int l7 = tid - 448;                            // wave-7 lane if >= 0
    float hlb_r = (l7 >= 0 && l7 < NC_) ? h2lb[l7] : 0.f;
    __syncthreads();

    int p = 0;
    for (int t = 0; t <= S_; ++t) {
        float ga0 = 0.f, ga1 = 0.f, ga2 = 0.f;
        float ar = 0.f, az = 0.f, an = 0.f;
        if (mv) {
            if (t < S_) {
                if (q == 0) {
                    const float* g = gi_lin + ((size_t)t * B_ + b) * G3;
                    ga0 = g[j]; ga1 = g[100 + j]; ga2 = g[200 + j];
                }
                MATVEC_REG(hhalf[p])
            }
        } else if (l7 >= 0 && t >= 1) {
            // wave 7: logits for step t-1 from f32 hf
            float v = -INFINITY;
            if (l7 < 40) {
                int c = l7 >> 2, part = l7 & 3;
                float acc = 0.f;
                int k0 = 26 * part, k1 = (k0 + 26 < H_) ? k0 + 26 : H_;
                for (int k = k0; k < k1; ++k) acc += hl_s[c * H_ + k] * hf[k];
                acc += __shfl_xor(acc, 1);
                acc += __shfl_xor(acc, 2);
                v = acc;                           // all 4 lanes hold class total
            }
            float src = __shfl(v, (l7 < NC_) ? 4 * l7 : 0);
            float lv = (l7 < NC_) ? src + hlb_r : -INFINITY;
            float mx = lv; int am = (l7 < 16) ? l7 : 15;
#pragma unroll
            for (int m = 8; m; m >>= 1) {          // 16-lane group reduce
                float ov = __shfl_xor(mx, m);
                int   oa = __shfl_xor(am, m);
                if (ov > mx || (ov == mx && oa < am)) { mx = ov; am = oa; }
            }
            float e = (l7 < NC_) ? __expf(lv - mx) : 0.f;
            float se = e;
#pragma unroll
            for (int m = 8; m; m >>= 1) se += __shfl_xor(se, m);
            float lse = mx + __logf(se);
            if (l7 < NC_) out[((size_t)(t - 1) * B_ + b) * NC_ + l7] = lv - lse;
            if (l7 == 0) prev_s = am;
        }
        __syncthreads();   // prev_s ready; hf consumed by logits
        if (t < S_ && mv && q == 0) {
            const float* tc = tc_s + prev_s * G3;
            float r = sigmoidf_(ga0 + tc[j]       + ar + bhr);
            float z = sigmoidf_(ga1 + tc[100 + j] + az + bhz);
            float n = tanhf_(   ga2 + tc[200 + j] + r * (an + bhn));
            float hn = (1.f - z) * n + z * hc;
            hc = hn;
            hf[j] = hn;
            hhalf[p ^ 1][j] = (_Float16)hn;
        }
        __syncthreads();   // h(t) visible for next matvec + logits
        p ^= 1;
    }
}

// ---------------------------------------------------------------------------
extern "C" void kernel_launch(void* const* d_in, const int* in_sizes, int n_in,
                              void* d_out, int out_size, void* d_ws, size_t ws_size,
                              hipStream_t stream)
{
    const float* hs   = (const float*)d_in[0];
    const int*   cb   = (const int*)  d_in[1];
    const float* fc5w = (const float*)d_in[2];
    const float* fc5b = (const float*)d_in[3];
    const float* ewif = (const float*)d_in[4];
    const float* ewhf = (const float*)d_in[5];
    const float* ebif = (const float*)d_in[6];
    const float* ebhf = (const float*)d_in[7];
    const float* ewib = (const float*)d_in[8];
    const float* ewhb = (const float*)d_in[9];
    const float* ebib = (const float*)d_in[10];
    const float* ebhb = (const float*)d_in[11];
    const float* emb  = (const float*)d_in[12];
    const float* l1w  = (const float*)d_in[13];
    const float* l1b  = (const float*)d_in[14];
    const float* dwih = (const float*)d_in[15];
    const float* dwhh = (const float*)d_in[16];
    const float* dbih = (const float*)d_in[17];
    const float* dbhh = (const float*)d_in[18];
    const float* h2lw = (const float*)d_in[19];
    const float* h2lb = (const float*)d_in[20];
    float* out = (float*)d_out;

    float* ws   = (float*)d_ws;
    float* doc  = ws;                  // [32*64, 768]   = 1572864
    float* gi   = doc  + 1572864;      // [2048, 600]    = 1228800
    float* out1 = gi   + 1228800;      // [2048, 200]    = 409600
    float* hT   = out1 + 409600;       // [64, 100]      = 6400
    float* W2   = hT   + 6400;         // [300, 200]     = 60000
    float* b2   = W2   + 60000;        // [300]
    float* tcg  = b2   + 320;          // [10, 300]      = 3000
    float* gil  = tcg  + 3072;         // [2048, 300]    = 614400

    pool_kernel<<<dim3(S_, B_), 256, 0, stream>>>(hs, cb, fc5w, fc5b, doc);
    w2_precompute<<<G3, 256, 0, stream>>>(dwih, l1w, l1b, emb, dbih, W2, b2, tcg);
    gemm_enc<<<dim3(10, 32), 256, 0, stream>>>(doc, ewif, ewib, ebif, ebib, gi);
    enc_scan<<<128, ENCT, 0, stream>>>(gi, ewhf, ewhb, ebhf, ebhb, out1, hT);
    {   // gil = out1 @ W2.T + b2   [2048,200]x[300,200] -> [2048,300]
        size_t sh = (size_t)(64 + 8) * 201 * sizeof(float);
        small_gemm<<<dim3(5, 256), 256, sh, stream>>>(out1, 200, 200,
                                                      W2, 200, 0, b2,
                                                      gil, 300, 300, 8, 64);
    }
    dec_scan<<<64, DECT, 0, stream>>>(gil, dwhh, dbhh, tcg,
                                      h2lw, h2lb, hT, out);
}